// Round 12
// baseline (369.369 us; speedup 1.0000x reference)
//
#include <hip/hip_runtime.h>
#include <hip/hip_bf16.h>

// B=2, S=2048, D=1024, H=16, DH=64, BLK=128, NB=16
// f32 inputs -> bf16 (one fused cvt). QKV in one dispatch (V written transposed).
// Attention: NO LDS staging of K/V (L2/L1-resident direct b128 reads), no barriers,
// wave-private P via LDS. Output projection -> f32 d_out.

typedef __attribute__((ext_vector_type(4))) float f32x4;
typedef __attribute__((ext_vector_type(8))) short bf16x8;

#define MFMA16(a, b, c) __builtin_amdgcn_mfma_f32_16x16x32_bf16(a, b, c, 0, 0, 0)
#define LOG2E 1.4426950408889634f

// ---------------- fused f32 -> bf16 (RNE) for x,Wq,Wk,Wv,Wo ----------------
__device__ inline unsigned short f2bf(float f) {
  unsigned u = __builtin_bit_cast(unsigned, f);
  unsigned rounding = 0x7FFFu + ((u >> 16) & 1u);
  return (unsigned short)((u + rounding) >> 16);
}

__global__ __launch_bounds__(256) void cvt_all(
    const float* __restrict__ x, const float* __restrict__ wq,
    const float* __restrict__ wk, const float* __restrict__ wv,
    const float* __restrict__ wo, unsigned short* __restrict__ dst) {
  const int i = blockIdx.x * 256 + threadIdx.x;  // unit = 8 elems; 1048576 units total
  if (i >= 1048576) return;
  const float* src;
  size_t off;
  if (i < 524288)      { src = x;  off = i; }
  else if (i < 655360) { src = wq; off = i - 524288; }
  else if (i < 786432) { src = wk; off = i - 655360; }
  else if (i < 917504) { src = wv; off = i - 786432; }
  else                 { src = wo; off = i - 917504; }
  const float4* p = (const float4*)src + off * 2;
  const float4 a = p[0], b = p[1];
  union { unsigned short u[8]; uint4 v; } r;
  r.u[0] = f2bf(a.x); r.u[1] = f2bf(a.y); r.u[2] = f2bf(a.z); r.u[3] = f2bf(a.w);
  r.u[4] = f2bf(b.x); r.u[5] = f2bf(b.y); r.u[6] = f2bf(b.z); r.u[7] = f2bf(b.w);
  *((uint4*)dst + i) = r.v;  // ws regions are contiguous: x | Wq | Wk | Wv | Wo
}

// ---------------- mask dtype sniffer ----------------
__device__ inline int mask_mode(const void* maskp) {
  const unsigned short* mh = (const unsigned short*)maskp;
  const unsigned* mw = (const unsigned*)maskp;
  bool anyFloatHalf = false;
  for (int t = 0; t < 128; ++t) {
    const unsigned short v = mh[t];
    if (v == 0x3F80u || v == 0x3C00u) { anyFloatHalf = true; break; }
  }
  if (anyFloatHalf) {
    bool evenNZ = false;
    for (int t = 0; t < 128; t += 2)
      if (mh[t] != 0) { evenNZ = true; break; }
    return evenNZ ? 1 : 0;  // 1 = bf16/f16, 0 = f32
  }
  bool anyBig = false;
  for (int t = 0; t < 64; ++t)
    if (mw[t] > 1u) { anyBig = true; break; }
  if (anyBig) return 2;  // packed u8
  bool oddNZ = false;
  for (int t = 1; t < 64; t += 2)
    if (mw[t] != 0u) { oddNZ = true; break; }
  return oddNZ ? 3 : 4;  // 3 = i32, 4 = i64
}

__device__ inline int mask_read(const void* maskp, int mode, int idx) {
  switch (mode) {
    case 0: return ((const unsigned*)maskp)[idx] != 0u;
    case 1: return ((const unsigned short*)maskp)[idx] != 0;
    case 2: return ((const unsigned char*)maskp)[idx] != 0;
    case 3: return ((const int*)maskp)[idx] != 0;
    default: return ((const unsigned*)maskp)[idx * 2] != 0u ||
                    ((const unsigned*)maskp)[idx * 2 + 1] != 0u;
  }
}

// ---------------- GEMM staging: 128x32 bf16 tile, linear ----------------
__device__ inline void stage_tile_128x32(const __hip_bfloat16* g, int ld_elems,
                                         __hip_bfloat16* lds, int wave, int lane) {
#pragma unroll
  for (int i = 0; i < 2; ++i) {
    const int chunk = wave * 2 + i;
    const int o = chunk * 1024 + lane * 16;
    const int r = o >> 6;
    const int cb = o & 63;
    const char* ga = (const char*)g + (size_t)r * ld_elems * 2 + cb;
    __builtin_amdgcn_global_load_lds(
        (const __attribute__((address_space(1))) unsigned int*)ga,
        (__attribute__((address_space(3))) unsigned int*)((char*)lds + chunk * 1024),
        16, 0, 0);
  }
}

// ---------------- fused QKV projection: grid (32, 24) ----------------
// y 0-7: Q -> QK[m][n]; y 8-15: K -> QK+4M; y 16-23: V^T -> Vt[b][1024][2048].
__global__ __launch_bounds__(256) void gemm_qkv(
    const __hip_bfloat16* __restrict__ A,
    const __hip_bfloat16* __restrict__ Wq, const __hip_bfloat16* __restrict__ Wk,
    const __hip_bfloat16* __restrict__ Wv,
    __hip_bfloat16* __restrict__ QK, __hip_bfloat16* __restrict__ Vt) {
  __shared__ __hip_bfloat16 sA[128 * 32];
  __shared__ __hip_bfloat16 sB[128 * 32];
  const int tid = threadIdx.x;
  const int wave = tid >> 6, lane = tid & 63;
  const int lr = lane & 15, lg = lane >> 4;
  const int wr = wave >> 1, wc = wave & 1;
  const int m0 = blockIdx.x * 128;
  const int sel = blockIdx.y >> 3;
  const int n0 = (blockIdx.y & 7) * 128;
  const __hip_bfloat16* W = (sel == 0) ? Wq : ((sel == 1) ? Wk : Wv);

  f32x4 acc[4][4] = {};
  for (int k0 = 0; k0 < 1024; k0 += 32) {
    stage_tile_128x32(A + (size_t)m0 * 1024 + k0, 1024, sA, wave, lane);
    stage_tile_128x32(W + (size_t)n0 * 1024 + k0, 1024, sB, wave, lane);
    __syncthreads();

    bf16x8 af[4], bfr[4];
#pragma unroll
    for (int mi = 0; mi < 4; ++mi)
      af[mi] = *(const bf16x8*)(sA + (64 * wr + 16 * mi + lr) * 32 + lg * 8);
#pragma unroll
    for (int ni = 0; ni < 4; ++ni)
      bfr[ni] = *(const bf16x8*)(sB + (64 * wc + 16 * ni + lr) * 32 + lg * 8);
    if (sel < 2) {
#pragma unroll
      for (int i = 0; i < 4; ++i)
#pragma unroll
        for (int jj = 0; jj < 4; ++jj)
          acc[i][jj] = MFMA16(af[i], bfr[jj], acc[i][jj]);
    } else {
#pragma unroll
      for (int i = 0; i < 4; ++i)
#pragma unroll
        for (int jj = 0; jj < 4; ++jj)
          acc[i][jj] = MFMA16(bfr[i], af[jj], acc[i][jj]);  // C^T = W . x^T
    }
    __syncthreads();
  }

  if (sel < 2) {
    __hip_bfloat16* OB = QK + (size_t)sel * 4194304ull;
#pragma unroll
    for (int i = 0; i < 4; ++i)
#pragma unroll
      for (int jj = 0; jj < 4; ++jj)
#pragma unroll
        for (int q = 0; q < 4; ++q) {
          const int m = m0 + 64 * wr + 16 * i + lg * 4 + q;
          const int n = n0 + 64 * wc + 16 * jj + lr;
          OB[(size_t)m * 1024 + n] = __float2bfloat16(acc[i][jj][q]);
        }
  } else {
#pragma unroll
    for (int i = 0; i < 4; ++i)
#pragma unroll
      for (int jj = 0; jj < 4; ++jj)
#pragma unroll
        for (int q = 0; q < 4; ++q) {
          const int n = n0 + 64 * wc + 16 * i + lg * 4 + q;
          const int m = m0 + 64 * wr + 16 * jj + lr;
          Vt[((size_t)(m >> 11) * 1024 + n) * 2048 + (m & 2047)] =
              __float2bfloat16(acc[i][jj][q]);
        }
  }
}

// ---------------- output projection + bias -> f32 ----------------
__global__ __launch_bounds__(256) void gemm_out(
    const __hip_bfloat16* __restrict__ A, const __hip_bfloat16* __restrict__ W,
    const float* __restrict__ bias, float* __restrict__ OutF) {
  __shared__ __hip_bfloat16 sA[128 * 32];
  __shared__ __hip_bfloat16 sB[128 * 32];
  const int tid = threadIdx.x;
  const int wave = tid >> 6, lane = tid & 63;
  const int lr = lane & 15, lg = lane >> 4;
  const int wr = wave >> 1, wc = wave & 1;
  const int m0 = blockIdx.x * 128;
  const int n0 = blockIdx.y * 128;

  f32x4 acc[4][4] = {};
  for (int k0 = 0; k0 < 1024; k0 += 32) {
    stage_tile_128x32(A + (size_t)m0 * 1024 + k0, 1024, sA, wave, lane);
    stage_tile_128x32(W + (size_t)n0 * 1024 + k0, 1024, sB, wave, lane);
    __syncthreads();

    bf16x8 af[4], bfr[4];
#pragma unroll
    for (int mi = 0; mi < 4; ++mi)
      af[mi] = *(const bf16x8*)(sA + (64 * wr + 16 * mi + lr) * 32 + lg * 8);
#pragma unroll
    for (int ni = 0; ni < 4; ++ni)
      bfr[ni] = *(const bf16x8*)(sB + (64 * wc + 16 * ni + lr) * 32 + lg * 8);
#pragma unroll
    for (int i = 0; i < 4; ++i)
#pragma unroll
      for (int jj = 0; jj < 4; ++jj)
        acc[i][jj] = MFMA16(af[i], bfr[jj], acc[i][jj]);
    __syncthreads();
  }

#pragma unroll
  for (int i = 0; i < 4; ++i)
#pragma unroll
    for (int jj = 0; jj < 4; ++jj)
#pragma unroll
      for (int q = 0; q < 4; ++q) {
        const int m = m0 + 64 * wr + 16 * i + lg * 4 + q;
        const int n = n0 + 64 * wc + 16 * jj + lr;
        OutF[(size_t)m * 1024 + n] = acc[i][jj][q] + bias[n];
      }
}

// ---------------- block-sparse flash attention (no LDS staging, no barriers) ----
// grid: (32 q-chunks of 64 rows, 32 b*h). 4 independent waves, wave owns 16 q rows.
// K and Vt fragments read directly from global (L1/L2-resident). Only P uses LDS.
__global__ __launch_bounds__(256, 4) void attn_kernel(
    const __hip_bfloat16* __restrict__ Q, const __hip_bfloat16* __restrict__ K,
    const __hip_bfloat16* __restrict__ Vt, const void* __restrict__ maskp,
    __hip_bfloat16* __restrict__ O) {
  __shared__ __hip_bfloat16 P_lds[4][16][136];

  const int qc = blockIdx.x, bh = blockIdx.y;
  const int b = bh >> 4, h = bh & 15;
  const int tid = threadIdx.x, wave = tid >> 6, lane = tid & 63;
  const int lr = lane & 15, lg = lane >> 4;

  const int mmode = mask_mode(maskp);
  const int qb = qc >> 1;  // mask row (128-row granularity)
  int keep[16], nkeep = 0;
  for (int j = 0; j < 16; ++j)
    if (mask_read(maskp, mmode, qb * 16 + j)) keep[nkeep++] = j;

  const size_t base = (size_t)b * 2048 * 1024 + (size_t)h * 64;  // Q/K/O elem base
  const char* Kbase = (const char*)(K + base);                   // row stride 2048B
  const char* Vtbase = (const char*)Vt +
      ((size_t)b * 1024 * 2048 + (size_t)h * 64 * 2048) * 2;     // row stride 4096B
  const int qrow0 = qc * 64 + wave * 16;

  bf16x8 qf[2];
#pragma unroll
  for (int ks = 0; ks < 2; ++ks)
    qf[ks] = *(const bf16x8*)(Q + base + (size_t)(qrow0 + lr) * 1024 + ks * 32 + lg * 8);

  f32x4 oa[4] = {};
  float mrun[4], lrun[4];
#pragma unroll
  for (int q = 0; q < 4; ++q) { mrun[q] = -1e30f; lrun[q] = 0.f; }

  for (int ji = 0; ji < nkeep; ++ji) {
    const int j = keep[ji];
    const char* gK = Kbase + (size_t)j * 128 * 2048;  // K rows s=j*128..
    const char* gV = Vtbase + (size_t)j * 128 * 2;    // Vt cols s=j*128..

    // ---- S = Q K^T (K fragments: direct global b128, L1/L2-hit) ----
    f32x4 s[8] = {};
    __builtin_amdgcn_s_setprio(1);
#pragma unroll
    for (int ks = 0; ks < 2; ++ks)
#pragma unroll
      for (int nt = 0; nt < 8; ++nt) {
        bf16x8 kf = *(const bf16x8*)(gK + (size_t)(16 * nt + lr) * 2048 + (ks * 32 + lg * 8) * 2);
        s[nt] = MFMA16(qf[ks], kf, s[nt]);
      }
    __builtin_amdgcn_s_setprio(0);

    // ---- online softmax (rows lg*4+q; 16-lane-group reduce) ----
#pragma unroll
    for (int q = 0; q < 4; ++q) {
      float rm = -1e30f;
#pragma unroll
      for (int nt = 0; nt < 8; ++nt) {
        s[nt][q] *= 0.125f;
        rm = fmaxf(rm, s[nt][q]);
      }
      rm = fmaxf(rm, __shfl_xor(rm, 1));
      rm = fmaxf(rm, __shfl_xor(rm, 2));
      rm = fmaxf(rm, __shfl_xor(rm, 4));
      rm = fmaxf(rm, __shfl_xor(rm, 8));
      const float mold = mrun[q];
      const float mnew = fmaxf(mold, rm);
      const float sf = exp2f((mold - mnew) * LOG2E);
      float rs = 0.f;
#pragma unroll
      for (int nt = 0; nt < 8; ++nt) {
        const float p = exp2f((s[nt][q] - mnew) * LOG2E);
        s[nt][q] = p;
        rs += p;
      }
      rs += __shfl_xor(rs, 1);
      rs += __shfl_xor(rs, 2);
      rs += __shfl_xor(rs, 4);
      rs += __shfl_xor(rs, 8);
      lrun[q] = lrun[q] * sf + rs;
      mrun[q] = mnew;
#pragma unroll
      for (int ni = 0; ni < 4; ++ni) oa[ni][q] *= sf;
    }

    // ---- P -> LDS (wave-private; same-wave lgkmcnt ordering, no barrier) ----
#pragma unroll
    for (int nt = 0; nt < 8; ++nt)
#pragma unroll
      for (int q = 0; q < 4; ++q)
        P_lds[wave][lg * 4 + q][16 * nt + lr] = __float2bfloat16(s[nt][q]);

    // ---- O += P V (V fragments: direct global b128, L1/L2-hit) ----
    __builtin_amdgcn_s_setprio(1);
#pragma unroll
    for (int ks = 0; ks < 4; ++ks) {
      bf16x8 pa = *(const bf16x8*)&P_lds[wave][lr][ks * 32 + lg * 8];
#pragma unroll
      for (int ni = 0; ni < 4; ++ni) {
        bf16x8 vb = *(const bf16x8*)(gV + (size_t)(16 * ni + lr) * 4096 + (ks * 32 + lg * 8) * 2);
        oa[ni] = MFMA16(pa, vb, oa[ni]);
      }
    }
    __builtin_amdgcn_s_setprio(0);
  }

  // ---- epilogue: O / l ----
#pragma unroll
  for (int ni = 0; ni < 4; ++ni)
#pragma unroll
    for (int q = 0; q < 4; ++q) {
      const int row = qrow0 + lg * 4 + q;
      const float v = oa[ni][q] / fmaxf(lrun[q], 1e-30f);
      O[base + (size_t)row * 1024 + 16 * ni + lr] = __float2bfloat16(v);
    }
}

extern "C" void kernel_launch(void* const* d_in, const int* in_sizes, int n_in,
                              void* d_out, int out_size, void* d_ws, size_t ws_size,
                              hipStream_t stream) {
  const float* x  = (const float*)d_in[0];
  const float* Wq = (const float*)d_in[1];
  const float* Wk = (const float*)d_in[2];
  const float* Wv = (const float*)d_in[3];
  const float* Wo = (const float*)d_in[4];
  const float* bo = (const float*)d_in[5];
  const void* mask = d_in[6];
  float* out = (float*)d_out;

  __hip_bfloat16* ws = (__hip_bfloat16*)d_ws;
  __hip_bfloat16* xb  = ws;                   // 4096x1024
  __hip_bfloat16* Wqb = ws + 4194304ull;      // 1024x1024
  __hip_bfloat16* Wkb = ws + 5242880ull;
  __hip_bfloat16* Wvb = ws + 6291456ull;
  __hip_bfloat16* Wob = ws + 7340032ull;
  __hip_bfloat16* Qb  = ws + 8388608ull;      // Q 4096x1024 | K 4096x1024
  __hip_bfloat16* Vtb = ws + 16777216ull;     // [2][1024][2048]
  __hip_bfloat16* Ob  = ws + 20971520ull;     // 4096x1024

  dim3 blk(256);
  // fused f32->bf16 for all inputs (ws regions contiguous)
  cvt_all<<<4096, blk, 0, stream>>>(x, Wq, Wk, Wv, Wo, (unsigned short*)xb);
  // fused Q,K,V^T projections
  gemm_qkv<<<dim3(32, 24), blk, 0, stream>>>(xb, Wqb, Wkb, Wvb, Qb, Vtb);
  // block-sparse flash attention (no barriers, direct global K/V)
  attn_kernel<<<dim3(32, 32), blk, 0, stream>>>(Qb, Qb + 4194304ull, Vtb, mask, Ob);
  // output projection + bias -> f32
  gemm_out<<<dim3(32, 8), blk, 0, stream>>>(Ob, Wob, bo, out);
}